// Round 5
// baseline (176.196 us; speedup 1.0000x reference)
//
#include <hip/hip_runtime.h>

typedef __attribute__((ext_vector_type(4))) int   int4v;
typedef __attribute__((ext_vector_type(4))) float float4v;

// XOR swizzle of the 16B slot within a 64B K-row (round-0 proven layout).
__device__ __forceinline__ int swz(int row, int slot) {
    return slot ^ ((row ^ (row >> 2)) & 3);
}

// Fake-quant grid index, bit-exact vs reference (round-3 validated):
// reciprocal fast path + rare exact-division tie fixup.
__device__ __forceinline__ int4v quant4(float4v v, float lo, float up,
                                        float scale, float inv) {
    float t0 = fminf(fmaxf(v[0], lo), up) - lo;
    float t1 = fminf(fmaxf(v[1], lo), up) - lo;
    float t2 = fminf(fmaxf(v[2], lo), up) - lo;
    float t3 = fminf(fmaxf(v[3], lo), up) - lo;
    float m0 = t0 * inv, m1 = t1 * inv, m2 = t2 * inv, m3 = t3 * inv;
    float r0 = rintf(m0), r1 = rintf(m1), r2 = rintf(m2), r3 = rintf(m3);
    float d0 = fabsf(fabsf(m0 - r0) - 0.5f);
    float d1 = fabsf(fabsf(m1 - r1) - 0.5f);
    float d2 = fabsf(fabsf(m2 - r2) - 0.5f);
    float d3 = fabsf(fabsf(m3 - r3) - 0.5f);
    if (fminf(fminf(d0, d1), fminf(d2, d3)) < 1e-4f) {   // rare tie-suspect
        r0 = rintf(t0 / scale); r1 = rintf(t1 / scale);
        r2 = rintf(t2 / scale); r3 = rintf(t3 / scale);
    }
    int4v q = {(int)r0, (int)r1, (int)r2, (int)r3};
    return q;
}

__device__ __forceinline__ unsigned bsum(int p) {        // sum of 4 bytes (<=15 each)
    return ((unsigned)p * 0x01010101u) >> 24;
}

// ---------------- kernel 1: quantize + pack + sums -> scratch ----------------
__global__ __launch_bounds__(256, 4) void quant_pack_kernel(
    const float* __restrict__ A, const float* __restrict__ B,
    const float* __restrict__ aLo, const float* __restrict__ aUp,
    const float* __restrict__ bLo, const float* __restrict__ bUp,
    int4v* __restrict__ qAg, int4v* __restrict__ qBg,
    float* __restrict__ RAg, float* __restrict__ CBg)
{
    __shared__ int qA[256 * 16];
    __shared__ int qB[256 * 16];

    const int tid = threadIdx.x;
    const int b   = blockIdx.x;

    const float lA = aLo[0], uA = aUp[0];
    const float lB = bLo[0], uB = bUp[0];
    const float sA = (uA - lA) / 15.0f;
    const float sB = (uB - lB) / 15.0f;
    const float iA = 1.0f / sA;
    const float iB = 1.0f / sB;

    const float4v* A4 = (const float4v*)(A + (size_t)b * 256 * 64);
    const float4v* B4 = (const float4v*)(B + (size_t)b * 64 * 256);

    // ---- stage A: dense coalesced float4 loads, pack 4 x i8 -> int (round-3)
    #pragma unroll
    for (int it = 0; it < 16; ++it) {
        int f = it * 256 + tid;
        float4v v = A4[f];
        int4v q = quant4(v, lA, uA, sA, iA);
        int p  = q[0] | (q[1] << 8) | (q[2] << 16) | (q[3] << 24);
        int row = f >> 4, chunk = f & 15;
        qA[row * 16 + swz(row, chunk >> 2) * 4 + (chunk & 3)] = p;
    }

    // ---- stage B: coalesced loads, transpose in regs (round-3) ----
    const int u  = tid & 63;
    const int kg = tid >> 6;
    #pragma unroll
    for (int kb = 0; kb < 4; ++kb) {
        int k0 = kb * 16 + kg * 4;
        int4v q0 = quant4(B4[(size_t)(k0 + 0) * 64 + u], lB, uB, sB, iB);
        int4v q1 = quant4(B4[(size_t)(k0 + 1) * 64 + u], lB, uB, sB, iB);
        int4v q2 = quant4(B4[(size_t)(k0 + 2) * 64 + u], lB, uB, sB, iB);
        int4v q3 = quant4(B4[(size_t)(k0 + 3) * 64 + u], lB, uB, sB, iB);
        #pragma unroll
        for (int c = 0; c < 4; ++c) {
            int col = u * 4 + c;
            int p = q0[c] | (q1[c] << 8) | (q2[c] << 16) | (q3[c] << 24);
            qB[col * 16 + swz(col, kb) * 4 + kg] = p;
        }
    }

    __syncthreads();

    // ---- row/col sums -> global (with +32*lA*lB baked, as before) ----
    {
        unsigned sa = 0, sb = 0;
        #pragma unroll
        for (int j = 0; j < 16; ++j) {
            unsigned pa = (unsigned)qA[tid * 16 + swz(tid, j >> 2) * 4 + (j & 3)];
            unsigned pb = (unsigned)qB[tid * 16 + swz(tid, j >> 2) * 4 + (j & 3)];
            sa += bsum(pa);
            sb += bsum(pb);
        }
        float c32 = 32.0f * lA * lB;
        RAg[b * 256 + tid] = sA * lB * (float)sa + c32;
        CBg[b * 256 + tid] = lA * sB * (float)sb + c32;
    }

    // ---- dump packed tiles (swizzled layout preserved), coalesced x4 ----
    const int4v* qa4 = (const int4v*)qA;
    const int4v* qb4 = (const int4v*)qB;
    #pragma unroll
    for (int i = 0; i < 4; ++i) {
        qAg[(size_t)b * 1024 + i * 256 + tid] = qa4[i * 256 + tid];
        qBg[(size_t)b * 1024 + i * 256 + tid] = qb4[i * 256 + tid];
    }
}

// ---------- kernel 2: pure MFMA + store; no LDS, no barriers ----------
__global__ __launch_bounds__(256, 4) void mm_store_kernel(
    const int4v* __restrict__ qAg, const int4v* __restrict__ qBg,
    const float* __restrict__ RAg, const float* __restrict__ CBg,
    const float* __restrict__ aLo, const float* __restrict__ aUp,
    const float* __restrict__ bLo, const float* __restrict__ bUp,
    float* __restrict__ Out)
{
    const int tid = threadIdx.x;
    const int b   = blockIdx.x;
    const int lane = tid & 63, wave = tid >> 6;
    const int lr = lane & 15, lk = lane >> 4;

    const float sA  = (aUp[0] - aLo[0]) / 15.0f;
    const float sB  = (bUp[0] - bLo[0]) / 15.0f;
    const float sAB = sA * sB;

    const int4v*   qa  = qAg + (size_t)b * 1024;
    const int4v*   qb  = qBg + (size_t)b * 1024;
    const float4v* ra4 = (const float4v*)(RAg + (size_t)b * 256);
    const float*   cbp = CBg + (size_t)b * 256;
    float* outb = Out + (size_t)b * 256 * 256;

    // afrag: per-instruction the wave covers a dense (permuted) 1KB chunk
    int4v   afrag[4];
    float4v RA[4];
    #pragma unroll
    for (int rt = 0; rt < 4; ++rt) {
        int row = wave * 64 + rt * 16 + lr;
        afrag[rt] = qa[row * 4 + swz(row, lk)];
        RA[rt]    = ra4[wave * 16 + rt * 4 + lk];   // rows orow..orow+3
    }

    const int4v z4 = {0, 0, 0, 0};
    #pragma unroll 4
    for (int ct = 0; ct < 16; ++ct) {
        int col = ct * 16 + lr;
        int4v bfrag = qb[col * 4 + swz(col, lk)];   // dense 1KB per instr
        float cb = cbp[col];
        #pragma unroll
        for (int rt = 0; rt < 4; ++rt) {
            int4v acc = __builtin_amdgcn_mfma_i32_16x16x64_i8(afrag[rt], bfrag, z4, 0, 0, 0);
            int orow = wave * 64 + rt * 16 + lk * 4;   // C/D: row=(lane>>4)*4+reg
            #pragma unroll
            for (int r = 0; r < 4; ++r) {
                outb[(size_t)(orow + r) * 256 + col] =
                    sAB * (float)acc[r] + RA[rt][r] + cb;
            }
        }
    }
}

// ---------------- fallback: round-3 monolithic (proven 98.6 us) ----------------
__global__ __launch_bounds__(256, 4) void qmm_kernel(
    const float* __restrict__ A, const float* __restrict__ B,
    const float* __restrict__ aLo, const float* __restrict__ aUp,
    const float* __restrict__ bLo, const float* __restrict__ bUp,
    float* __restrict__ Out)
{
    __shared__ int   qA[256 * 16];
    __shared__ int   qB[256 * 16];
    __shared__ float RAf[256];
    __shared__ float CBf[256];

    const int tid = threadIdx.x;
    const int b   = blockIdx.x;

    const float lA = aLo[0], uA = aUp[0];
    const float lB = bLo[0], uB = bUp[0];
    const float sA  = (uA - lA) / 15.0f;
    const float sB  = (uB - lB) / 15.0f;
    const float iA  = 1.0f / sA;
    const float iB  = 1.0f / sB;
    const float sAB = sA * sB;

    const float4v* A4 = (const float4v*)(A + (size_t)b * 256 * 64);
    const float4v* B4 = (const float4v*)(B + (size_t)b * 64 * 256);
    float* outb = Out + (size_t)b * 256 * 256;

    #pragma unroll
    for (int it = 0; it < 16; ++it) {
        int f = it * 256 + tid;
        float4v v = A4[f];
        int4v q = quant4(v, lA, uA, sA, iA);
        int p  = q[0] | (q[1] << 8) | (q[2] << 16) | (q[3] << 24);
        int row = f >> 4, chunk = f & 15;
        qA[row * 16 + swz(row, chunk >> 2) * 4 + (chunk & 3)] = p;
    }

    const int u  = tid & 63;
    const int kg = tid >> 6;
    #pragma unroll
    for (int kb = 0; kb < 4; ++kb) {
        int k0 = kb * 16 + kg * 4;
        int4v q0 = quant4(B4[(size_t)(k0 + 0) * 64 + u], lB, uB, sB, iB);
        int4v q1 = quant4(B4[(size_t)(k0 + 1) * 64 + u], lB, uB, sB, iB);
        int4v q2 = quant4(B4[(size_t)(k0 + 2) * 64 + u], lB, uB, sB, iB);
        int4v q3 = quant4(B4[(size_t)(k0 + 3) * 64 + u], lB, uB, sB, iB);
        #pragma unroll
        for (int c = 0; c < 4; ++c) {
            int col = u * 4 + c;
            int p = q0[c] | (q1[c] << 8) | (q2[c] << 16) | (q3[c] << 24);
            qB[col * 16 + swz(col, kb) * 4 + kg] = p;
        }
    }

    __syncthreads();

    {
        unsigned sa = 0, sb = 0;
        #pragma unroll
        for (int j = 0; j < 16; ++j) {
            unsigned pa = (unsigned)qA[tid * 16 + swz(tid, j >> 2) * 4 + (j & 3)];
            unsigned pb = (unsigned)qB[tid * 16 + swz(tid, j >> 2) * 4 + (j & 3)];
            sa += bsum(pa);
            sb += bsum(pb);
        }
        float c32 = 32.0f * lA * lB;
        RAf[tid] = sA * lB * (float)sa + c32;
        CBf[tid] = lA * sB * (float)sb + c32;
    }
    __syncthreads();

    const int wave = tid >> 6, lane = tid & 63;
    const int lr = lane & 15;
    const int lk = lane >> 4;

    int4v afrag[4];
    #pragma unroll
    for (int rt = 0; rt < 4; ++rt) {
        int row = wave * 64 + rt * 16 + lr;
        afrag[rt] = *(const int4v*)&qA[row * 16 + swz(row, lk) * 4];
    }

    #pragma unroll 4
    for (int ct = 0; ct < 16; ++ct) {
        int col = ct * 16 + lr;
        int4v bfrag = *(const int4v*)&qB[col * 16 + swz(col, lk) * 4];
        float cb = CBf[col];
        #pragma unroll
        for (int rt = 0; rt < 4; ++rt) {
            int4v acc = {0, 0, 0, 0};
            acc = __builtin_amdgcn_mfma_i32_16x16x64_i8(afrag[rt], bfrag, acc, 0, 0, 0);
            int orow = wave * 64 + rt * 16 + lk * 4;
            #pragma unroll
            for (int r = 0; r < 4; ++r) {
                outb[(size_t)(orow + r) * 256 + col] =
                    sAB * (float)acc[r] + RAf[orow + r] + cb;
            }
        }
    }
}

extern "C" void kernel_launch(void* const* d_in, const int* in_sizes, int n_in,
                              void* d_out, int out_size, void* d_ws, size_t ws_size,
                              hipStream_t stream) {
    const float* A   = (const float*)d_in[0];
    const float* B   = (const float*)d_in[1];
    const float* aLo = (const float*)d_in[2];
    const float* aUp = (const float*)d_in[3];
    const float* bLo = (const float*)d_in[4];
    const float* bUp = (const float*)d_in[5];
    float* Out = (float*)d_out;

    int batches = in_sizes[0] / (256 * 64);   // 128*8 = 1024
    size_t need = (size_t)batches * (16384u * 2 + 1024u * 2);   // 34 KB/batch

    if (ws_size >= need) {
        char* w = (char*)d_ws;
        int4v* qAg = (int4v*)w;
        int4v* qBg = (int4v*)(w + (size_t)batches * 16384);
        float* RAg = (float*)(w + (size_t)batches * 32768);
        float* CBg = (float*)(w + (size_t)batches * 32768 + (size_t)batches * 1024);
        quant_pack_kernel<<<batches, 256, 0, stream>>>(A, B, aLo, aUp, bLo, bUp,
                                                       qAg, qBg, RAg, CBg);
        mm_store_kernel<<<batches, 256, 0, stream>>>(qAg, qBg, RAg, CBg,
                                                     aLo, aUp, bLo, bUp, Out);
    } else {
        qmm_kernel<<<batches, 256, 0, stream>>>(A, B, aLo, aUp, bLo, bUp, Out);
    }
}

// Round 6
// 101.854 us; speedup vs baseline: 1.7299x; 1.7299x over previous
//
#include <hip/hip_runtime.h>

typedef __attribute__((ext_vector_type(4)))  int   int4v;
typedef __attribute__((ext_vector_type(16))) int   int16v;
typedef __attribute__((ext_vector_type(4)))  float float4v;

// XOR swizzle of the 16B slot within a 64B K-row (round-0 proven layout).
__device__ __forceinline__ int swz(int row, int slot) {
    return slot ^ ((row ^ (row >> 2)) & 3);
}

// Fake-quant grid index, bit-exact vs reference (round-3 validated):
// reciprocal fast path + rare exact-division tie fixup.
__device__ __forceinline__ int4v quant4(float4v v, float lo, float up,
                                        float scale, float inv) {
    float t0 = fminf(fmaxf(v[0], lo), up) - lo;
    float t1 = fminf(fmaxf(v[1], lo), up) - lo;
    float t2 = fminf(fmaxf(v[2], lo), up) - lo;
    float t3 = fminf(fmaxf(v[3], lo), up) - lo;
    float m0 = t0 * inv, m1 = t1 * inv, m2 = t2 * inv, m3 = t3 * inv;
    float r0 = rintf(m0), r1 = rintf(m1), r2 = rintf(m2), r3 = rintf(m3);
    float d0 = fabsf(fabsf(m0 - r0) - 0.5f);
    float d1 = fabsf(fabsf(m1 - r1) - 0.5f);
    float d2 = fabsf(fabsf(m2 - r2) - 0.5f);
    float d3 = fabsf(fabsf(m3 - r3) - 0.5f);
    if (fminf(fminf(d0, d1), fminf(d2, d3)) < 1e-4f) {   // rare tie-suspect
        r0 = rintf(t0 / scale); r1 = rintf(t1 / scale);
        r2 = rintf(t2 / scale); r3 = rintf(t3 / scale);
    }
    int4v q = {(int)r0, (int)r1, (int)r2, (int)r3};
    return q;
}

__device__ __forceinline__ unsigned bsum(int p) {        // sum of 4 bytes (<=15 each)
    return ((unsigned)p * 0x01010101u) >> 24;
}

__global__ __launch_bounds__(256, 4) void qmm_kernel(
    const float* __restrict__ A, const float* __restrict__ B,
    const float* __restrict__ aLo, const float* __restrict__ aUp,
    const float* __restrict__ bLo, const float* __restrict__ bUp,
    float* __restrict__ Out)
{
    // qA: [row 0..255][k 0..63] i8 (16B slot = 16 consecutive k), slot-swizzled
    // qB: B^T -> [col 0..255][k 0..63] i8, same layout
    __shared__ int   qA[256 * 16];
    __shared__ int   qB[256 * 16];
    __shared__ float RAf[256];   // sA*lB*rowsum(qA[i]) + 32*lA*lB
    __shared__ float CBf[256];   // lA*sB*colsum(qB[j]) + 32*lA*lB

    const int tid = threadIdx.x;
    const int b   = blockIdx.x;

    const float lA = aLo[0], uA = aUp[0];
    const float lB = bLo[0], uB = bUp[0];
    const float sA  = (uA - lA) / 15.0f;
    const float sB  = (uB - lB) / 15.0f;
    const float iA  = 1.0f / sA;
    const float iB  = 1.0f / sB;
    const float sAB = sA * sB;

    const float4v* A4 = (const float4v*)(A + (size_t)b * 256 * 64);
    const float4v* B4 = (const float4v*)(B + (size_t)b * 64 * 256);
    float* outb = Out + (size_t)b * 256 * 256;

    // ---- stage A: dense coalesced float4 loads (1KB/instr), pack 4 x i8 -> int
    #pragma unroll
    for (int it = 0; it < 16; ++it) {
        int f = it * 256 + tid;            // float4 index 0..4095
        float4v v = A4[f];
        int4v q = quant4(v, lA, uA, sA, iA);
        int p  = q[0] | (q[1] << 8) | (q[2] << 16) | (q[3] << 24);
        int row = f >> 4, chunk = f & 15;  // row 0..255, 16 ints per row
        qA[row * 16 + swz(row, chunk >> 2) * 4 + (chunk & 3)] = p;
    }

    // ---- stage B: coalesced loads of 4x4 fp32 tile, transpose in regs ----
    const int u  = tid & 63;   // column group: cols 4u..4u+3
    const int kg = tid >> 6;   // wave id -> 4-byte offset inside 16B k-slot
    #pragma unroll
    for (int kb = 0; kb < 4; ++kb) {
        int k0 = kb * 16 + kg * 4;         // k rows k0..k0+3
        int4v q0 = quant4(B4[(size_t)(k0 + 0) * 64 + u], lB, uB, sB, iB);
        int4v q1 = quant4(B4[(size_t)(k0 + 1) * 64 + u], lB, uB, sB, iB);
        int4v q2 = quant4(B4[(size_t)(k0 + 2) * 64 + u], lB, uB, sB, iB);
        int4v q3 = quant4(B4[(size_t)(k0 + 3) * 64 + u], lB, uB, sB, iB);
        #pragma unroll
        for (int c = 0; c < 4; ++c) {
            int col = u * 4 + c;
            int p = q0[c] | (q1[c] << 8) | (q2[c] << 16) | (q3[c] << 24);
            qB[col * 16 + swz(col, kb) * 4 + kg] = p;
        }
    }

    __syncthreads();

    // ---- row sums of qA / col sums of B (rows of qB), byte-sum trick ----
    {
        unsigned sa = 0, sb = 0;
        #pragma unroll
        for (int j = 0; j < 16; ++j) {
            unsigned pa = (unsigned)qA[tid * 16 + swz(tid, j >> 2) * 4 + (j & 3)];
            unsigned pb = (unsigned)qB[tid * 16 + swz(tid, j >> 2) * 4 + (j & 3)];
            sa += bsum(pa);
            sb += bsum(pb);
        }
        float c32 = 32.0f * lA * lB;
        RAf[tid] = sA * lB * (float)sa + c32;
        CBf[tid] = lA * sB * (float)sb + c32;
    }
    __syncthreads();

    // ---- compute: 32x32x32 i8 MFMA; every store covers full 128B lines ----
    // Wave w owns rows 64w..64w+63 (2 tile-rows of 32), all 8 tile-cols.
    // A/B operand: lane = row/col (lane&31), k-half = lane>>5, 16B contiguous k.
    // C/D: col = lane&31, row = (reg&3) + 8*(reg>>2) + 4*(lane>>5).
    const int lane = tid & 63, wave = tid >> 6;
    const int ln = lane & 31, h = lane >> 5;

    const int4v* qA4 = (const int4v*)qA;
    const int4v* qB4 = (const int4v*)qB;
    const int16v z16 = {0,0,0,0,0,0,0,0,0,0,0,0,0,0,0,0};

    #pragma unroll
    for (int tr = 0; tr < 2; ++tr) {
        const int rbase = wave * 64 + tr * 32;
        const int arow  = rbase + ln;
        int4v af0 = qA4[arow * 4 + swz(arow, 0 + h)];   // kstep 0, bytes h*16..
        int4v af1 = qA4[arow * 4 + swz(arow, 2 + h)];   // kstep 1

        float4v RA[4];
        #pragma unroll
        for (int g = 0; g < 4; ++g)
            RA[g] = *(const float4v*)&RAf[rbase + 8 * g + 4 * h];

        #pragma unroll 2
        for (int ct = 0; ct < 8; ++ct) {
            const int col = ct * 32 + ln;
            int4v bf0 = qB4[col * 4 + swz(col, 0 + h)];
            int4v bf1 = qB4[col * 4 + swz(col, 2 + h)];
            float cb  = CBf[col];

            int16v acc = __builtin_amdgcn_mfma_i32_32x32x32_i8(af0, bf0, z16, 0, 0, 0);
            acc        = __builtin_amdgcn_mfma_i32_32x32x32_i8(af1, bf1, acc, 0, 0, 0);

            #pragma unroll
            for (int g = 0; g < 4; ++g) {
                const int row0 = rbase + 8 * g + 4 * h;
                #pragma unroll
                for (int j = 0; j < 4; ++j) {
                    // lanes 0-31: one full 128B line; lanes 32-63: another
                    outb[(size_t)(row0 + j) * 256 + col] =
                        fmaf(sAB, (float)acc[g * 4 + j], RA[g][j] + cb);
                }
            }
        }
    }
}

extern "C" void kernel_launch(void* const* d_in, const int* in_sizes, int n_in,
                              void* d_out, int out_size, void* d_ws, size_t ws_size,
                              hipStream_t stream) {
    const float* A   = (const float*)d_in[0];
    const float* B   = (const float*)d_in[1];
    const float* aLo = (const float*)d_in[2];
    const float* aUp = (const float*)d_in[3];
    const float* bLo = (const float*)d_in[4];
    const float* bUp = (const float*)d_in[5];
    float* Out = (float*)d_out;

    int batches = in_sizes[0] / (256 * 64);   // 128*8 = 1024
    qmm_kernel<<<batches, 256, 0, stream>>>(A, B, aLo, aUp, bLo, bUp, Out);
}